// Round 6
// baseline (5603.671 us; speedup 1.0000x reference)
//
#include <hip/hip_runtime.h>
#include <hip/hip_bf16.h>

#define B_  64
#define T_  12
#define N_  325
#define DIN 2
#define H_  128
#define BN  (B_*N_)    // 20800
#define DPITCH 384     // padded node pitch (k-extent)
#define AROWS 384      // padded m-rows per support matrix

typedef __hip_bfloat16 bf16;
typedef unsigned short u16;
typedef __attribute__((ext_vector_type(8))) short short8;
typedef __attribute__((ext_vector_type(4))) float f32x4;

__device__ __forceinline__ float b2f(bf16 v){ return __bfloat162float(v); }
__device__ __forceinline__ u16 f2b(float f){
    __hip_bfloat16 h = __float2bfloat16(f);
    return *reinterpret_cast<u16*>(&h);
}
__device__ __forceinline__ float ldf(const void* p, size_t i, int bf){
    return bf ? b2f(((const bf16*)p)[i]) : ((const float*)p)[i];
}

// async global->LDS, 16B per lane; dest = base + lane*16 (wave-uniform base)
__device__ __forceinline__ void gl_lds16(const u16* g, u16* l){
    __builtin_amdgcn_global_load_lds(
        (const __attribute__((address_space(1))) unsigned int*)g,
        (__attribute__((address_space(3))) unsigned int*)l, 16, 0, 0);
}

// ---------------------------------------------------------------------------
// A-matrix double-buffer scheme (race-free rh fusion):
//   F_A = [x | h | S-slots of [x,h]]     (gemm0's A; fill + d1)
//   F_B = [x | r*h | S-slots of [x,r*h]] (gemm1's A; fill/d1 dup x-cols,
//                                         gemm0 r-blocks write r*h, d2 h-cols)
// Both pitch KCP (64-aligned). Pad cols annihilated by zero Wt rows (finite).
// ---------------------------------------------------------------------------
struct FillCfg { u16 *F, *F2, *Ft; const float *x, *h; long xbs; int C, KCP, Cpad, Din, b0, nb; };
struct DiffCfg { u16 *F, *Fd; const u16* Ft; int C, KCP, Cpad, coff0, tpb, T, fcmax, Din, nb; };
struct GemmCfg { const u16* Fb; const u16* Wt; const float* bias; float* zr; float* hb;
                 u16 *Fw, *Ft; int KCP, rows, gy, ct, Din, Cpad, nb; };

// ---------------------------------------------------------------------------
__global__ void sniff(const void* __restrict__ sup, int* __restrict__ flag){
    if (threadIdx.x == 0 && blockIdx.x == 0){
        float sb = 0.f, sf = 0.f;
        for (int n = 0; n < N_; ++n){
            sb += b2f(((const bf16*)sup)[n]);
            sf += ((const float*)sup)[n];
        }
        float db = fabsf(sb - 1.f), df = fabsf(sf - 1.f);
        *flag = (db < df) ? 1 : 0;
    }
}

struct CvtArgs { const void* src[12]; float* dst[12]; int n[12]; };

__global__ void cvt_all(CvtArgs a, const int* __restrict__ flag){
    int ii = blockIdx.y;
    int i  = blockIdx.x*256 + threadIdx.x;
    if (i >= a.n[ii]) return;
    a.dst[ii][i] = ldf(a.src[ii], i, *flag);
}

// ---------------------------------------------------------------------------
__global__ void support_prep(const void* __restrict__ sup, const int* __restrict__ flag,
                             float* __restrict__ msq){
    int bf = *flag;
    int s = blockIdx.z;
    int m = blockIdx.y*16 + threadIdx.y;
    int n = blockIdx.x*16 + threadIdx.x;
    __shared__ float As[16][17], Bs[16][17];
    size_t base = (size_t)s*N_*N_;
    float acc = 0.f;
    for (int j0 = 0; j0 < N_; j0 += 16){
        As[threadIdx.y][threadIdx.x] = (m < N_ && j0+threadIdx.x < N_) ? ldf(sup, base + (size_t)m*N_ + j0+threadIdx.x, bf) : 0.f;
        Bs[threadIdx.y][threadIdx.x] = (j0+threadIdx.y < N_ && n < N_) ? ldf(sup, base + (size_t)(j0+threadIdx.y)*N_ + n, bf) : 0.f;
        __syncthreads();
        #pragma unroll
        for (int jj=0; jj<16; ++jj) acc += As[threadIdx.y][jj]*Bs[jj][threadIdx.x];
        __syncthreads();
    }
    if (m < N_ && n < N_){
        msq[(size_t)(2*s  )*N_*N_ + m*N_ + n] = ldf(sup, base + (size_t)m*N_ + n, bf);
        msq[(size_t)(2*s+1)*N_*N_ + m*N_ + n] = acc;
    }
}

__global__ void asq_prep(const float* __restrict__ msq, u16* __restrict__ asq){
    int idx = blockIdx.x*256 + threadIdx.x;
    int total = 4*AROWS*DPITCH;
    if (idx >= total) return;
    int col = idx % DPITCH;
    int rm  = idx / DPITCH;
    int m   = rm % AROWS;
    int k   = rm / AROWS;
    asq[idx] = (m < N_ && col < N_) ? f2b(msq[((size_t)k*N_ + m)*N_ + col]) : 0;
}

// ---------------------------------------------------------------------------
__global__ __launch_bounds__(256) void wtrans(const void* __restrict__ W, u16* __restrict__ Wt,
                                              int KC, int Nout, int KCpad,
                                              const int* __restrict__ flag){
    int bf = *flag;
    int k0 = blockIdx.x*64, c0 = blockIdx.y*64;
    int tid = threadIdx.x;
    __shared__ u16 T[64][72];
    #pragma unroll
    for (int it=0; it<2; ++it){
        int lin = it*256 + tid;
        int kl = lin >> 3, seg = lin & 7;
        int gk = k0 + kl, gc = c0 + seg*8;
        u16 tmp[8];
        #pragma unroll
        for (int e=0;e<8;++e) tmp[e] = (gk < KC) ? f2b(ldf(W, (size_t)gk*Nout + gc + e, bf)) : 0;
        *(uint4*)&T[kl][seg*8] = *(const uint4*)tmp;
    }
    __syncthreads();
    #pragma unroll
    for (int it=0; it<2; ++it){
        int lin = it*256 + tid;
        int cl = lin >> 3, seg = lin & 7;
        u16 tmp[8];
        #pragma unroll
        for (int j=0;j<8;++j) tmp[j] = T[seg*8+j][cl];
        *(uint4*)(Wt + (size_t)(c0+cl)*KCpad + k0 + seg*8) = *(const uint4*)tmp;
    }
}

// ---------------------------------------------------------------------------
// fill_k: F_A slot0 = [x|h], F_B slot0 x-part dup, Ft = transpose. Dual-cfg.
// ---------------------------------------------------------------------------
__global__ __launch_bounds__(256) void fill_k(FillCfg ca, FillCfg cb, int na){
    int bi = blockIdx.x;
    FillCfg c = ca;
    if (bi >= na){ c = cb; bi -= na; }
    int gyc  = (c.C + 63) >> 6;
    int nblk = bi % 6;
    int rest = bi / 6;
    int cblk = rest % gyc;
    int bl   = rest / gyc;
    int bg = c.b0 + bl;
    int n0 = nblk*64, c0 = cblk*64;
    int tid = threadIdx.x;
    __shared__ u16 T[64][72];
    #pragma unroll
    for (int it=0; it<2; ++it){
        int lin = it*256 + tid;
        int nl = lin >> 3, seg = lin & 7;
        int gn = n0 + nl;
        u16 tmp[8];
        #pragma unroll
        for (int e=0;e<8;++e){
            int cc = c0 + seg*8 + e;
            float v = 0.f;
            if (gn < N_ && cc < c.C)
                v = (cc < c.Din) ? c.x[(size_t)bg*c.xbs + (size_t)gn*c.Din + cc]
                                 : c.h[((size_t)bg*N_ + gn)*H_ + (cc - c.Din)];
            tmp[e] = f2b(v);
        }
        *(uint4*)&T[nl][seg*8] = *(const uint4*)tmp;
        if (gn < N_){
            int cbase = c0 + seg*8;
            size_t roff = ((size_t)bl*N_ + gn)*c.KCP + cbase;
            u16* dst = c.F + roff;
            if (cbase + 7 < c.C){
                *(uint4*)dst = *(const uint4*)tmp;
            } else {
                #pragma unroll
                for (int e=0;e<8;++e) if (cbase + e < c.C) dst[e] = tmp[e];
            }
            if (cbase < c.Din){
                u16* dst2 = c.F2 + roff;
                if (cbase + 7 < c.Din){
                    *(uint4*)dst2 = *(const uint4*)tmp;
                } else {
                    #pragma unroll
                    for (int e=0;e<8;++e) if (cbase + e < c.Din) dst2[e] = tmp[e];
                }
            }
        }
    }
    __syncthreads();
    #pragma unroll
    for (int it=0; it<2; ++it){
        int lin = it*256 + tid;
        int cl = lin >> 3, seg = lin & 7;
        if (c0 + cl < c.C){
            u16 tmp[8];
            #pragma unroll
            for (int j=0;j<8;++j) tmp[j] = T[seg*8+j][cl];
            *(uint4*)(c.Ft + ((size_t)bl*c.Cpad + (size_t)(c0+cl))*DPITCH + n0 + seg*8)
                = *(const uint4*)tmp;
        }
    }
}

// ---------------------------------------------------------------------------
// diffuse_k: 128m x 64c tile, flat (batch x channel) c-tiling, XCD-pinned.
// C-write goes to F; columns cc < Din are duplicated into Fd (d1 keeps the
// S*x columns of F_B fresh; d2 passes Din=0 -> no dup).
// ---------------------------------------------------------------------------
__global__ __launch_bounds__(256) void diffuse_k(DiffCfg ca, DiffCfg cb, int na,
                                                 const u16* __restrict__ asq){
    int bi = blockIdx.x;
    DiffCfg c = ca;
    if (bi >= na){ c = cb; bi -= na; }
    int xcd = bi & 7, m8 = bi >> 3;
    int tg = m8 / 12, s = m8 % 12;
    int t = tg*8 + xcd;
    if (t >= c.T) return;
    int y = s % 3, k = s / 3;
    int fc0;
    if (c.tpb){
        int blb = t / c.tpb, tb = t - blb*c.tpb;
        fc0 = blb*c.Cpad + c.coff0 + tb*64;
    } else {
        fc0 = t*64;
    }
    int bl0  = fc0 / c.Cpad;
    int rem0 = fc0 - bl0*c.Cpad;

    const u16* A    = asq + (size_t)k*AROWS*DPITCH;
    const u16* Bt_g = c.Ft + (size_t)fc0*DPITCH;

    int m0 = y * 128;
    int tid = threadIdx.x;
    int wv = tid >> 6, lane = tid & 63, l15 = lane & 15, quad = lane >> 4;
    int lr = lane >> 3, ls = lane & 7;

    __shared__ u16 As[128*64];
    __shared__ u16 Bs[64*64];

    f32x4 acc[2][4];
    #pragma unroll
    for (int i2=0;i2<2;++i2)
        #pragma unroll
        for (int j=0;j<4;++j) acc[i2][j] = (f32x4){0.f,0.f,0.f,0.f};

    for (int k0 = 0; k0 < N_; k0 += 64){
        #pragma unroll
        for (int j=0;j<4;++j){
            int row = wv*32 + j*8 + lr;
            int seg = ls ^ lr;
            gl_lds16(A + (size_t)(m0+row)*DPITCH + k0 + seg*8, &As[(wv*32 + j*8)*64]);
        }
        #pragma unroll
        for (int j=0;j<2;++j){
            int row = wv*16 + j*8 + lr;
            int seg = ls ^ lr;
            gl_lds16(Bt_g + (size_t)row*DPITCH + k0 + seg*8, &Bs[(wv*16 + j*8)*64]);
        }
        __syncthreads();
        #pragma unroll
        for (int ks = 0; ks < 64; ks += 32){
            int sw = (((ks>>3) + quad) ^ (l15 & 7)) << 3;
            short8 a0 = *(const short8*)&As[(wv*32      + l15)*64 + sw];
            short8 a1 = *(const short8*)&As[(wv*32 + 16 + l15)*64 + sw];
            short8 b0 = *(const short8*)&Bs[(     l15)*64 + sw];
            short8 b1 = *(const short8*)&Bs[(16 + l15)*64 + sw];
            short8 b2 = *(const short8*)&Bs[(32 + l15)*64 + sw];
            short8 b3 = *(const short8*)&Bs[(48 + l15)*64 + sw];
            acc[0][0] = __builtin_amdgcn_mfma_f32_16x16x32_bf16(a0,b0,acc[0][0],0,0,0);
            acc[0][1] = __builtin_amdgcn_mfma_f32_16x16x32_bf16(a0,b1,acc[0][1],0,0,0);
            acc[0][2] = __builtin_amdgcn_mfma_f32_16x16x32_bf16(a0,b2,acc[0][2],0,0,0);
            acc[0][3] = __builtin_amdgcn_mfma_f32_16x16x32_bf16(a0,b3,acc[0][3],0,0,0);
            acc[1][0] = __builtin_amdgcn_mfma_f32_16x16x32_bf16(a1,b0,acc[1][0],0,0,0);
            acc[1][1] = __builtin_amdgcn_mfma_f32_16x16x32_bf16(a1,b1,acc[1][1],0,0,0);
            acc[1][2] = __builtin_amdgcn_mfma_f32_16x16x32_bf16(a1,b2,acc[1][2],0,0,0);
            acc[1][3] = __builtin_amdgcn_mfma_f32_16x16x32_bf16(a1,b3,acc[1][3],0,0,0);
        }
        __syncthreads();
    }
    #pragma unroll
    for (int j=0;j<4;++j){
        int d  = j*16 + l15;
        int cr = rem0 + d;
        int wrap = (cr >= c.Cpad) ? 1 : 0;
        int bl = bl0 + wrap;
        int cc = wrap ? (cr - c.Cpad) : cr;
        int ok = (fc0 + d) < c.fcmax;
        size_t off = (size_t)bl*N_*c.KCP + (size_t)(k+1)*c.C + cc;
        u16* Cm = c.F  + off;
        u16* Cd = c.Fd + off;
        int dup = cc < c.Din;
        #pragma unroll
        for (int i2=0;i2<2;++i2){
            #pragma unroll
            for (int r=0;r<4;++r){
                int m = m0 + wv*32 + i2*16 + quad*4 + r;
                if (ok && m < N_){
                    u16 v = f2b(acc[i2][j][r]);
                    Cm[(size_t)m*c.KCP] = v;
                    if (dup) Cd[(size_t)m*c.KCP] = v;
                }
            }
        }
    }
}

// ---------------------------------------------------------------------------
// gemm_k: 128m x 64c, async staging + swizzle, XCD-pinned, dual-cfg.
// MODE 0, z-blocks (c0<128): zr[gr*128+cc] = sigmoid.
// MODE 0, r-blocks (c0>=128): rh = sigmoid*h -> F_B slot0-h + LDS-transposed
//   Ft h-rows (rhfill_k fused; race-free since gemm0 reads F_A only).
// MODE 1: GRU update, reads zr pitch 128, A = F_B.
// ---------------------------------------------------------------------------
template<int MODE>
__global__ __launch_bounds__(256) void gemm_k(GemmCfg ca, GemmCfg cb, int na){
    int bi = blockIdx.x;
    GemmCfg c = ca;
    if (bi >= na){ c = cb; bi -= na; }
    int xcd = bi & 7, q = bi >> 3;
    int cbk = q % c.ct;
    int rt  = (q / c.ct)*8 + xcd;
    if (rt >= c.gy) return;
    int r0 = rt * 128;
    int c0 = cbk * 64;
    int tid = threadIdx.x;
    int wv = tid >> 6, lane = tid & 63, l15 = lane & 15, quad = lane >> 4;
    int lr = lane >> 3, ls = lane & 7;

    __shared__ u16 SM[128*64 + 64*64];
    u16* As = SM;
    u16* Bs = SM + 128*64;

    f32x4 acc[2][4];
    #pragma unroll
    for (int i2=0;i2<2;++i2)
        #pragma unroll
        for (int j=0;j<4;++j) acc[i2][j] = (f32x4){0.f,0.f,0.f,0.f};

    for (int k0 = 0; k0 < c.KCP; k0 += 64){
        #pragma unroll
        for (int j=0;j<4;++j){
            int row = wv*32 + j*8 + lr;
            int seg = ls ^ lr;
            gl_lds16(c.Fb + (size_t)(r0+row)*c.KCP + k0 + seg*8, &As[(wv*32 + j*8)*64]);
        }
        #pragma unroll
        for (int j=0;j<2;++j){
            int row = wv*16 + j*8 + lr;
            int seg = ls ^ lr;
            gl_lds16(c.Wt + (size_t)(c0+row)*c.KCP + k0 + seg*8, &Bs[(wv*16 + j*8)*64]);
        }
        __syncthreads();
        #pragma unroll
        for (int ks = 0; ks < 64; ks += 32){
            int sw = (((ks>>3) + quad) ^ (l15 & 7)) << 3;
            short8 a0 = *(const short8*)&As[(wv*32      + l15)*64 + sw];
            short8 a1 = *(const short8*)&As[(wv*32 + 16 + l15)*64 + sw];
            short8 b0 = *(const short8*)&Bs[(     l15)*64 + sw];
            short8 b1 = *(const short8*)&Bs[(16 + l15)*64 + sw];
            short8 b2 = *(const short8*)&Bs[(32 + l15)*64 + sw];
            short8 b3 = *(const short8*)&Bs[(48 + l15)*64 + sw];
            acc[0][0] = __builtin_amdgcn_mfma_f32_16x16x32_bf16(a0,b0,acc[0][0],0,0,0);
            acc[0][1] = __builtin_amdgcn_mfma_f32_16x16x32_bf16(a0,b1,acc[0][1],0,0,0);
            acc[0][2] = __builtin_amdgcn_mfma_f32_16x16x32_bf16(a0,b2,acc[0][2],0,0,0);
            acc[0][3] = __builtin_amdgcn_mfma_f32_16x16x32_bf16(a0,b3,acc[0][3],0,0,0);
            acc[1][0] = __builtin_amdgcn_mfma_f32_16x16x32_bf16(a1,b0,acc[1][0],0,0,0);
            acc[1][1] = __builtin_amdgcn_mfma_f32_16x16x32_bf16(a1,b1,acc[1][1],0,0,0);
            acc[1][2] = __builtin_amdgcn_mfma_f32_16x16x32_bf16(a1,b2,acc[1][2],0,0,0);
            acc[1][3] = __builtin_amdgcn_mfma_f32_16x16x32_bf16(a1,b3,acc[1][3],0,0,0);
        }
        __syncthreads();
    }

    if (MODE == 1){
        #pragma unroll
        for (int i2=0;i2<2;++i2){
            #pragma unroll
            for (int j=0;j<4;++j){
                int cc = c0 + j*16 + l15;
                #pragma unroll
                for (int r=0;r<4;++r){
                    int gr = r0 + wv*32 + i2*16 + quad*4 + r;
                    if (gr >= c.rows) continue;
                    float v = acc[i2][j][r] + c.bias[cc];
                    float hc   = tanhf(v);
                    float z    = c.zr[(size_t)gr*128 + cc];
                    float hold = c.hb[(size_t)gr*128 + cc];
                    c.hb[(size_t)gr*128 + cc] = z*hold + (1.f - z)*hc;
                }
            }
        }
    } else if (c0 < 128){
        // z-blocks
        #pragma unroll
        for (int i2=0;i2<2;++i2){
            #pragma unroll
            for (int j=0;j<4;++j){
                int cc = c0 + j*16 + l15;
                #pragma unroll
                for (int r=0;r<4;++r){
                    int gr = r0 + wv*32 + i2*16 + quad*4 + r;
                    if (gr >= c.rows) continue;
                    float v = acc[i2][j][r] + c.bias[cc];
                    c.zr[(size_t)gr*128 + cc] = 1.f/(1.f + __expf(-v));
                }
            }
        }
    } else {
        // r-blocks: rh = sigmoid(v)*h; write F_B slot0-h + transpose to Ft
        int ch0 = c0 - 128;
        #pragma unroll
        for (int j=0;j<4;++j){
            int chl = j*16 + l15;
            int ch  = ch0 + chl;
            float bs = c.bias[c0 + chl];
            #pragma unroll
            for (int i2=0;i2<2;++i2){
                #pragma unroll
                for (int r=0;r<4;++r){
                    int grl = wv*32 + i2*16 + quad*4 + r;
                    int gr  = r0 + grl;
                    u16 pb = 0;
                    if (gr < c.rows){
                        float v  = acc[i2][j][r] + bs;
                        float rr = 1.f/(1.f + __expf(-v));
                        float hv = c.hb[(size_t)gr*128 + ch];
                        pb = f2b(rr * hv);
                        c.Fw[(size_t)gr*c.KCP + c.Din + ch] = pb;
                    }
                    SM[chl*136 + grl] = pb;
                }
            }
        }
        __syncthreads();
        int cl = tid >> 2, part = tid & 3;
        int ch = ch0 + cl;
        #pragma unroll
        for (int c4=0;c4<4;++c4){
            int grl = part*32 + c4*8;
            int gr  = r0 + grl;
            if (gr >= c.rows) continue;
            int bl = gr / N_;
            int n  = gr - bl*N_;
            u16* frow = c.Ft + ((size_t)bl*c.Cpad + c.Din + ch)*DPITCH;
            const u16* src = &SM[cl*136 + grl];
            if (gr + 7 < c.rows && n + 8 <= N_){
                if ((n & 7) == 0){
                    *(uint4*)(frow + n) = *(const uint4*)src;
                } else if ((n & 1) == 0){
                    #pragma unroll
                    for (int e=0;e<4;++e)
                        *(unsigned*)(frow + n + 2*e) = *(const unsigned*)(src + 2*e);
                } else {
                    #pragma unroll
                    for (int e=0;e<8;++e) frow[n + e] = src[e];
                }
            } else {
                for (int e=0;e<8;++e){
                    int g = gr + e;
                    if (g < c.rows){
                        int b2 = g / N_;
                        int n2 = g - b2*N_;
                        c.Ft[((size_t)b2*c.Cpad + c.Din + ch)*DPITCH + n2] = src[e];
                    }
                }
            }
        }
    }
}

// ---------------------------------------------------------------------------
__global__ __launch_bounds__(256) void proj(const float* __restrict__ h1,
                                            const float* __restrict__ Wp,
                                            const float* __restrict__ bp,
                                            float* __restrict__ xdec,
                                            float* __restrict__ out, int t){
    int row  = blockIdx.x * 4 + (threadIdx.x >> 6);
    int lane = threadIdx.x & 63;
    float v0 = h1[(size_t)row*128 + lane];
    float v1 = h1[(size_t)row*128 + 64 + lane];
    float w00 = Wp[lane*2+0],      w01 = Wp[lane*2+1];
    float w10 = Wp[(64+lane)*2+0], w11 = Wp[(64+lane)*2+1];
    float a0 = v0*w00 + v1*w10;
    float a1 = v0*w01 + v1*w11;
    #pragma unroll
    for (int off=32; off>0; off>>=1){
        a0 += __shfl_down(a0, off);
        a1 += __shfl_down(a1, off);
    }
    if (lane == 0){
        a0 += bp[0];
        a1 += bp[1];
        xdec[(size_t)row*2+0] = a0;
        xdec[(size_t)row*2+1] = a1;
        int b = row / N_, n = row % N_;
        size_t o = ((size_t)(b*T_ + t)*N_ + n)*2;
        out[o]   = a0;
        out[o+1] = a1;
    }
}

// ---------------------------------------------------------------------------
struct Layer {
    u16 *F, *F2, *Ft; float *zr; float *h;
    const u16 *Wg, *Wc; const float *bg, *bc;
    int C, KCP, Din, Cpad;
};

extern "C" void kernel_launch(void* const* d_in, const int* in_sizes, int n_in,
                              void* d_out, int out_size, void* d_ws, size_t ws_size,
                              hipStream_t stream){
    float* out = (float*)d_out;

    char* pb = (char*)d_ws;
    auto alloc = [&](size_t bytes)->void*{
        void* r = (void*)pb;
        pb += (bytes + 255) & ~(size_t)255;
        return r;
    };

    int* flag = (int*)alloc(16);
    sniff<<<1, 64, 0, stream>>>(d_in[2], flag);

    const int idxs[11] = {0,4,6,8,10,12,14,16,18,19,20};
    float* cw[21] = {nullptr};
    CvtArgs ca;
    int maxn = 0;
    for (int ii = 0; ii < 11; ++ii){
        int i = idxs[ii];
        int n = in_sizes[i];
        cw[i] = (float*)alloc((size_t)n*4);
        ca.src[ii] = d_in[i];
        ca.dst[ii] = cw[i];
        ca.n[ii]   = n;
        if (n > maxn) maxn = n;
    }
    cvt_all<<<dim3((maxn+255)/256, 11), 256, 0, stream>>>(ca, flag);
    const float* src = cw[0];

    float* msq  = (float*)alloc((size_t)4*N_*N_*4);
    float* h0   = (float*)alloc((size_t)BN*H_*4);
    float* h1   = (float*)alloc((size_t)BN*H_*4);
    float* xdec = (float*)alloc((size_t)BN*DIN*4);
    u16*   asq  = (u16*)alloc((size_t)4*AROWS*DPITCH*2);

    const int widx[8]  = {3,5,7,9,11,13,15,17};
    const int wKC[8]   = {650,650,1280,1280,650,650,1280,1280};
    const int wNout[8] = {256,128,256,128,256,128,256,128};
    u16* wt[8];
    for (int i=0;i<8;++i){
        int KCpad = (wKC[i] + 63) & ~63;
        wt[i] = (u16*)alloc((size_t)wNout[i]*KCpad*2);
        wtrans<<<dim3(KCpad/64, wNout[i]/64), 256, 0, stream>>>(d_in[widx[i]], wt[i], wKC[i], wNout[i], KCpad, flag);
    }

    {
        dim3 g((N_+15)/16, (N_+15)/16, 2), b(16,16);
        support_prep<<<g, b, 0, stream>>>(d_in[2], flag, msq);
        int tot = 4*AROWS*DPITCH;
        asq_prep<<<dim3((tot+255)/256), 256, 0, stream>>>(msq, asq);
    }
    hipMemsetAsync(h0, 0, sizeof(float)*(size_t)BN*H_*2, stream);  // h0 and h1

    // ---- dual (layer-pipelined encoder) sizing ----
    size_t fixed = (size_t)(pb - (char*)d_ws);
    size_t need0 = (size_t)BN*128*4 + 2*(size_t)BN*704*2  + (size_t)B_*130*DPITCH*2;
    size_t need1 = (size_t)BN*128*4 + 2*(size_t)BN*1280*2 + (size_t)B_*256*DPITCH*2;
    bool dual = (fixed + need0 + need1 + (4<<20)) <= ws_size;

    auto mkFill = [&](Layer& L, const float* x, long xbs, int b0, int Bc)->FillCfg{
        return FillCfg{L.F, L.F2, L.Ft, x, L.h, xbs, L.C, L.KCP, L.Cpad, L.Din, b0,
                       6*((L.C+63)>>6)*Bc};
    };
    auto mkD1 = [&](Layer& L, int Bc)->DiffCfg{
        int fcmax = Bc*L.Cpad;
        int T = fcmax >> 6;
        return DiffCfg{L.F, L.F2, L.Ft, L.C, L.KCP, L.Cpad, 0, 0, T, fcmax, L.Din,
                       12*(((T+7)/8)*8)};
    };
    auto mkD2 = [&](Layer& L, int Bc)->DiffCfg{
        int T = Bc*2;
        return DiffCfg{L.F2, L.F2, L.Ft, L.C, L.KCP, L.Cpad, L.Din, 2, T, Bc*L.Cpad, 0,
                       12*(((T+7)/8)*8)};
    };
    auto mkG0 = [&](Layer& L, int b0, int Bc)->GemmCfg{
        int rows = Bc*N_, gy = (rows+127)/128;
        return GemmCfg{L.F, L.Wg, L.bg, L.zr, L.h + (size_t)b0*N_*H_,
                       L.F2, L.Ft, L.KCP, rows, gy, 4, L.Din, L.Cpad,
                       8*((gy+7)/8)*4};
    };
    auto mkG1 = [&](Layer& L, int b0, int Bc)->GemmCfg{
        int rows = Bc*N_, gy = (rows+127)/128;
        return GemmCfg{L.F2, L.Wc, L.bc, L.zr, L.h + (size_t)b0*N_*H_,
                       L.F2, L.Ft, L.KCP, rows, gy, 2, L.Din, L.Cpad,
                       8*((gy+7)/8)*2};
    };
    auto runCellSeq = [&](Layer& L, const float* x, long xbs, int b0, int Bc){
        FillCfg f = mkFill(L, x, xbs, b0, Bc);
        fill_k<<<dim3(f.nb), 256, 0, stream>>>(f, f, f.nb);
        DiffCfg d1 = mkD1(L, Bc);
        diffuse_k<<<dim3(d1.nb), 256, 0, stream>>>(d1, d1, d1.nb, asq);
        GemmCfg g0 = mkG0(L, b0, Bc);
        gemm_k<0><<<dim3(g0.nb), 256, 0, stream>>>(g0, g0, g0.nb);
        DiffCfg d2 = mkD2(L, Bc);
        diffuse_k<<<dim3(d2.nb), 256, 0, stream>>>(d2, d2, d2.nb, asq);
        GemmCfg g1 = mkG1(L, b0, Bc);
        gemm_k<1><<<dim3(g1.nb), 256, 0, stream>>>(g1, g1, g1.nb);
    };

    if (dual){
        float* zr0 = (float*)alloc((size_t)BN*128*4);
        u16*   F0a = (u16*)alloc((size_t)BN*704*2);
        u16*   F0b = (u16*)alloc((size_t)BN*704*2);
        u16*   Ft0 = (u16*)alloc((size_t)B_*130*DPITCH*2);
        float* zr1 = (float*)alloc((size_t)BN*128*4);
        u16*   F1a = (u16*)alloc((size_t)BN*1280*2);
        u16*   F1b = (u16*)alloc((size_t)BN*1280*2);
        u16*   Ft1 = (u16*)alloc((size_t)B_*256*DPITCH*2);
        alloc(1<<19);  // slack for OOB-row DMA

        // one-time zero: L0 pad cols (650..703) stay finite-zero forever
        hipMemsetAsync(F0a, 0, (size_t)BN*704*2, stream);
        hipMemsetAsync(F0b, 0, (size_t)BN*704*2, stream);

        Layer E0{F0a, F0b, Ft0, zr0, h0, wt[0], wt[1], cw[4],  cw[6],  130, 704,  2,   130};
        Layer E1{F1a, F1b, Ft1, zr1, h1, wt[2], wt[3], cw[8],  cw[10], 256, 1280, 128, 256};
        Layer D0{F0a, F0b, Ft0, zr0, h0, wt[4], wt[5], cw[12], cw[14], 130, 704,  2,   130};
        Layer D1{F1a, F1b, Ft1, zr1, h1, wt[6], wt[7], cw[16], cw[18], 256, 1280, 128, 256};

        // ------- encoder: layer-pipelined super-steps -------
        for (int s = 0; s <= T_; ++s){
            bool has0 = (s < T_), has1 = (s >= 1);
            const float* x0 = src + (size_t)s*N_*DIN;
            FillCfg f0 = mkFill(E0, x0, (long)T_*N_*DIN, 0, B_);
            FillCfg f1 = mkFill(E1, h0, (long)N_*H_,     0, B_);
            if (has0 && has1) fill_k<<<dim3(f0.nb+f1.nb),256,0,stream>>>(f0, f1, f0.nb);
            else if (has0)    fill_k<<<dim3(f0.nb),256,0,stream>>>(f0, f0, f0.nb);
            else              fill_k<<<dim3(f1.nb),256,0,stream>>>(f1, f1, f1.nb);

            DiffCfg a1 = mkD1(E0, B_), b1 = mkD1(E1, B_);
            if (has0 && has1) diffuse_k<<<dim3(a1.nb+b1.nb),256,0,stream>>>(a1, b1, a1.nb, asq);
            else if (has0)    diffuse_k<<<dim3(a1.nb),256,0,stream>>>(a1, a1, a1.nb, asq);
            else              diffuse_k<<<dim3(b1.nb),256,0,stream>>>(b1, b1, b1.nb, asq);

            GemmCfg ga = mkG0(E0, 0, B_), gb = mkG0(E1, 0, B_);
            if (has0 && has1) gemm_k<0><<<dim3(ga.nb+gb.nb),256,0,stream>>>(ga, gb, ga.nb);
            else if (has0)    gemm_k<0><<<dim3(ga.nb),256,0,stream>>>(ga, ga, ga.nb);
            else              gemm_k<0><<<dim3(gb.nb),256,0,stream>>>(gb, gb, gb.nb);

            DiffCfg a2 = mkD2(E0, B_), b2 = mkD2(E1, B_);
            if (has0 && has1) diffuse_k<<<dim3(a2.nb+b2.nb),256,0,stream>>>(a2, b2, a2.nb, asq);
            else if (has0)    diffuse_k<<<dim3(a2.nb),256,0,stream>>>(a2, a2, a2.nb, asq);
            else              diffuse_k<<<dim3(b2.nb),256,0,stream>>>(b2, b2, b2.nb, asq);

            GemmCfg ha = mkG1(E0, 0, B_), hb = mkG1(E1, 0, B_);
            if (has0 && has1) gemm_k<1><<<dim3(ha.nb+hb.nb),256,0,stream>>>(ha, hb, ha.nb);
            else if (has0)    gemm_k<1><<<dim3(ha.nb),256,0,stream>>>(ha, ha, ha.nb);
            else              gemm_k<1><<<dim3(hb.nb),256,0,stream>>>(hb, hb, hb.nb);
        }

        // ------- decoder: serial (proj feedback) -------
        hipMemsetAsync(xdec, 0, sizeof(float)*(size_t)BN*DIN, stream);
        for (int t = 0; t < T_; ++t){
            runCellSeq(D0, xdec, (long)N_*DIN, 0, B_);
            runCellSeq(D1, h0,   (long)N_*H_,  0, B_);
            proj<<<dim3(BN/4), 256, 0, stream>>>(h1, cw[19], cw[20], xdec, out, t);
        }
    } else {
        // ------- fallback: sequential with adaptive chunking -------
        size_t perb = (size_t)N_*(2*1280*2 + 128*4) + (size_t)256*DPITCH*2;
        int Bc = 64;
        while (Bc > 2 && fixed + (1<<20) + (size_t)Bc*perb > ws_size) Bc >>= 1;
        float* zr = (float*)alloc((size_t)Bc*N_*128*4);
        u16*   Fa = (u16*)alloc((size_t)Bc*N_*1280*2);
        u16*   Fb = (u16*)alloc((size_t)Bc*N_*1280*2);
        u16*   Ft = (u16*)alloc((size_t)Bc*256*DPITCH*2);
        alloc(1<<19);

        hipMemsetAsync(Fa, 0, (size_t)Bc*N_*1280*2, stream);
        hipMemsetAsync(Fb, 0, (size_t)Bc*N_*1280*2, stream);

        Layer SE0{Fa, Fb, Ft, zr, h0, wt[0], wt[1], cw[4],  cw[6],  130, 704,  2,   130};
        Layer SE1{Fa, Fb, Ft, zr, h1, wt[2], wt[3], cw[8],  cw[10], 256, 1280, 128, 256};
        Layer SD0{Fa, Fb, Ft, zr, h0, wt[4], wt[5], cw[12], cw[14], 130, 704,  2,   130};
        Layer SD1{Fa, Fb, Ft, zr, h1, wt[6], wt[7], cw[16], cw[18], 256, 1280, 128, 256};

        for (int t = 0; t < T_; ++t){
            for (int b0 = 0; b0 < B_; b0 += Bc)
                runCellSeq(SE0, src + (size_t)t*N_*DIN, (long)T_*N_*DIN, b0, Bc);
            for (int b0 = 0; b0 < B_; b0 += Bc)
                runCellSeq(SE1, h0, (long)N_*H_, b0, Bc);
        }
        hipMemsetAsync(xdec, 0, sizeof(float)*(size_t)BN*DIN, stream);
        for (int t = 0; t < T_; ++t){
            for (int b0 = 0; b0 < B_; b0 += Bc)
                runCellSeq(SD0, xdec, (long)N_*DIN, b0, Bc);
            for (int b0 = 0; b0 < B_; b0 += Bc)
                runCellSeq(SD1, h0, (long)N_*H_, b0, Bc);
            proj<<<dim3(BN/4), 256, 0, stream>>>(h1, cw[19], cw[20], xdec, out, t);
        }
    }
}

// Round 7
// 5014.359 us; speedup vs baseline: 1.1175x; 1.1175x over previous
//
#include <hip/hip_runtime.h>
#include <hip/hip_bf16.h>

#define B_  64
#define T_  12
#define N_  325
#define DIN 2
#define H_  128
#define BN  (B_*N_)    // 20800
#define DPITCH 384     // padded node pitch (k-extent)
#define AROWS 384      // padded m-rows per support matrix

typedef __hip_bfloat16 bf16;
typedef unsigned short u16;
typedef __attribute__((ext_vector_type(8))) short short8;
typedef __attribute__((ext_vector_type(4))) float f32x4;

__device__ __forceinline__ float b2f(bf16 v){ return __bfloat162float(v); }
__device__ __forceinline__ u16 f2b(float f){
    __hip_bfloat16 h = __float2bfloat16(f);
    return *reinterpret_cast<u16*>(&h);
}
__device__ __forceinline__ float ldf(const void* p, size_t i, int bf){
    return bf ? b2f(((const bf16*)p)[i]) : ((const float*)p)[i];
}

// async global->LDS, 16B per lane; dest = base + lane*16 (wave-uniform base)
__device__ __forceinline__ void gl_lds16(const u16* g, u16* l){
    __builtin_amdgcn_global_load_lds(
        (const __attribute__((address_space(1))) unsigned int*)g,
        (__attribute__((address_space(3))) unsigned int*)l, 16, 0, 0);
}

// ---------------------------------------------------------------------------
// F row pitch = KCP (64-aligned: 704 L0 / 1280 L1). Pad cols are finite zeros
// (one-time memset; Wt rows >= KC are zero) -> exact +0.0 in MFMA.
// ---------------------------------------------------------------------------
struct FillCfg { u16 *F, *Ft; const float *x, *h; long xbs; int C, KCP, Cpad, Din, b0, nb; };
struct DiffCfg { u16* F; const u16* Ft; int C, KCP, Cpad, coff0, tpb, T, fcmax, nb; };
struct GemmCfg { const u16* Fb; const u16* Wt; const float* bias; float* zr; float* hb;
                 int KCP, rows, gy, ct, nb; };
struct RhCfg  { u16 *F, *Ft; const float *zr, *h; int KCP, Cpad, Din, b0, nb; };

// ---------------------------------------------------------------------------
__global__ void sniff(const void* __restrict__ sup, int* __restrict__ flag){
    if (threadIdx.x == 0 && blockIdx.x == 0){
        float sb = 0.f, sf = 0.f;
        for (int n = 0; n < N_; ++n){
            sb += b2f(((const bf16*)sup)[n]);
            sf += ((const float*)sup)[n];
        }
        float db = fabsf(sb - 1.f), df = fabsf(sf - 1.f);
        *flag = (db < df) ? 1 : 0;
    }
}

struct CvtArgs { const void* src[12]; float* dst[12]; int n[12]; };

__global__ void cvt_all(CvtArgs a, const int* __restrict__ flag){
    int ii = blockIdx.y;
    int i  = blockIdx.x*256 + threadIdx.x;
    if (i >= a.n[ii]) return;
    a.dst[ii][i] = ldf(a.src[ii], i, *flag);
}

// ---------------------------------------------------------------------------
__global__ void support_prep(const void* __restrict__ sup, const int* __restrict__ flag,
                             float* __restrict__ msq){
    int bf = *flag;
    int s = blockIdx.z;
    int m = blockIdx.y*16 + threadIdx.y;
    int n = blockIdx.x*16 + threadIdx.x;
    __shared__ float As[16][17], Bs[16][17];
    size_t base = (size_t)s*N_*N_;
    float acc = 0.f;
    for (int j0 = 0; j0 < N_; j0 += 16){
        As[threadIdx.y][threadIdx.x] = (m < N_ && j0+threadIdx.x < N_) ? ldf(sup, base + (size_t)m*N_ + j0+threadIdx.x, bf) : 0.f;
        Bs[threadIdx.y][threadIdx.x] = (j0+threadIdx.y < N_ && n < N_) ? ldf(sup, base + (size_t)(j0+threadIdx.y)*N_ + n, bf) : 0.f;
        __syncthreads();
        #pragma unroll
        for (int jj=0; jj<16; ++jj) acc += As[threadIdx.y][jj]*Bs[jj][threadIdx.x];
        __syncthreads();
    }
    if (m < N_ && n < N_){
        msq[(size_t)(2*s  )*N_*N_ + m*N_ + n] = ldf(sup, base + (size_t)m*N_ + n, bf);
        msq[(size_t)(2*s+1)*N_*N_ + m*N_ + n] = acc;
    }
}

__global__ void asq_prep(const float* __restrict__ msq, u16* __restrict__ asq){
    int idx = blockIdx.x*256 + threadIdx.x;
    int total = 4*AROWS*DPITCH;
    if (idx >= total) return;
    int col = idx % DPITCH;
    int rm  = idx / DPITCH;
    int m   = rm % AROWS;
    int k   = rm / AROWS;
    asq[idx] = (m < N_ && col < N_) ? f2b(msq[((size_t)k*N_ + m)*N_ + col]) : 0;
}

// ---------------------------------------------------------------------------
__global__ __launch_bounds__(256) void wtrans(const void* __restrict__ W, u16* __restrict__ Wt,
                                              int KC, int Nout, int KCpad,
                                              const int* __restrict__ flag){
    int bf = *flag;
    int k0 = blockIdx.x*64, c0 = blockIdx.y*64;
    int tid = threadIdx.x;
    __shared__ u16 T[64][72];
    #pragma unroll
    for (int it=0; it<2; ++it){
        int lin = it*256 + tid;
        int kl = lin >> 3, seg = lin & 7;
        int gk = k0 + kl, gc = c0 + seg*8;
        u16 tmp[8];
        #pragma unroll
        for (int e=0;e<8;++e) tmp[e] = (gk < KC) ? f2b(ldf(W, (size_t)gk*Nout + gc + e, bf)) : 0;
        *(uint4*)&T[kl][seg*8] = *(const uint4*)tmp;
    }
    __syncthreads();
    #pragma unroll
    for (int it=0; it<2; ++it){
        int lin = it*256 + tid;
        int cl = lin >> 3, seg = lin & 7;
        u16 tmp[8];
        #pragma unroll
        for (int j=0;j<8;++j) tmp[j] = T[seg*8+j][cl];
        *(uint4*)(Wt + (size_t)(c0+cl)*KCpad + k0 + seg*8) = *(const uint4*)tmp;
    }
}

// ---------------------------------------------------------------------------
// fill_k: F slot0 = [x|h] AND Ft = transpose. Dual-cfg merged grid.
// ---------------------------------------------------------------------------
__global__ __launch_bounds__(256) void fill_k(FillCfg ca, FillCfg cb, int na){
    int bi = blockIdx.x;
    FillCfg c = ca;
    if (bi >= na){ c = cb; bi -= na; }
    int gyc  = (c.C + 63) >> 6;
    int nblk = bi % 6;
    int rest = bi / 6;
    int cblk = rest % gyc;
    int bl   = rest / gyc;
    int bg = c.b0 + bl;
    int n0 = nblk*64, c0 = cblk*64;
    int tid = threadIdx.x;
    __shared__ u16 T[64][72];
    #pragma unroll
    for (int it=0; it<2; ++it){
        int lin = it*256 + tid;
        int nl = lin >> 3, seg = lin & 7;
        int gn = n0 + nl;
        u16 tmp[8];
        #pragma unroll
        for (int e=0;e<8;++e){
            int cc = c0 + seg*8 + e;
            float v = 0.f;
            if (gn < N_ && cc < c.C)
                v = (cc < c.Din) ? c.x[(size_t)bg*c.xbs + (size_t)gn*c.Din + cc]
                                 : c.h[((size_t)bg*N_ + gn)*H_ + (cc - c.Din)];
            tmp[e] = f2b(v);
        }
        *(uint4*)&T[nl][seg*8] = *(const uint4*)tmp;
        if (gn < N_){
            int cbase = c0 + seg*8;
            u16* dst = c.F + ((size_t)bl*N_ + gn)*c.KCP + cbase;
            if (cbase + 7 < c.C){
                *(uint4*)dst = *(const uint4*)tmp;
            } else {
                #pragma unroll
                for (int e=0;e<8;++e) if (cbase + e < c.C) dst[e] = tmp[e];
            }
        }
    }
    __syncthreads();
    #pragma unroll
    for (int it=0; it<2; ++it){
        int lin = it*256 + tid;
        int cl = lin >> 3, seg = lin & 7;
        if (c0 + cl < c.C){
            u16 tmp[8];
            #pragma unroll
            for (int j=0;j<8;++j) tmp[j] = T[seg*8+j][cl];
            *(uint4*)(c.Ft + ((size_t)bl*c.Cpad + (size_t)(c0+cl))*DPITCH + n0 + seg*8)
                = *(const uint4*)tmp;
        }
    }
}

// ---------------------------------------------------------------------------
// rhfill_k: F[slot0 h-part] = Ft[h-rows] = bf16(r * h), vectorized LDS
// transpose. Grid: nblk(6) x cblk(2) x bl(Bc). Dual-cfg merged grid.
// ---------------------------------------------------------------------------
__global__ __launch_bounds__(256) void rhfill_k(RhCfg ca, RhCfg cb, int na){
    int bi = blockIdx.x;
    RhCfg c = ca;
    if (bi >= na){ c = cb; bi -= na; }
    int nblk = bi % 6;
    int rest = bi / 6;
    int cblk = rest & 1;
    int bl   = rest >> 1;
    int bg = c.b0 + bl;
    int n0 = nblk*64, ch0 = cblk*64;
    int tid = threadIdx.x;
    __shared__ u16 T[64][72];
    #pragma unroll
    for (int it=0; it<2; ++it){
        int lin = it*256 + tid;
        int nl = lin >> 3, seg = lin & 7;
        int gn = n0 + nl;
        u16 tmp[8];
        if (gn < N_){
            size_t rloc = (size_t)bl*N_ + gn;     // chunk-local row (zr, F)
            size_t rg   = (size_t)bg*N_ + gn;     // global row (h)
            const float* zp = c.zr + rloc*256 + 128 + ch0 + seg*8;
            const float* hp = c.h  + rg*128 + ch0 + seg*8;
            float4 z0 = *(const float4*)zp, z1 = *(const float4*)(zp+4);
            float4 h0 = *(const float4*)hp, h1 = *(const float4*)(hp+4);
            tmp[0]=f2b(z0.x*h0.x); tmp[1]=f2b(z0.y*h0.y);
            tmp[2]=f2b(z0.z*h0.z); tmp[3]=f2b(z0.w*h0.w);
            tmp[4]=f2b(z1.x*h1.x); tmp[5]=f2b(z1.y*h1.y);
            tmp[6]=f2b(z1.z*h1.z); tmp[7]=f2b(z1.w*h1.w);
            u16* fp = c.F + rloc*c.KCP + c.Din + ch0 + seg*8;
            #pragma unroll
            for (int e=0;e<4;++e){
                unsigned w = (unsigned)tmp[2*e] | ((unsigned)tmp[2*e+1] << 16);
                *(unsigned*)(fp + 2*e) = w;
            }
        } else {
            #pragma unroll
            for (int e=0;e<8;++e) tmp[e] = 0;
        }
        *(uint4*)&T[nl][seg*8] = *(const uint4*)tmp;
    }
    __syncthreads();
    #pragma unroll
    for (int it=0; it<2; ++it){
        int lin = it*256 + tid;
        int cl = lin >> 3, seg = lin & 7;
        u16 tmp[8];
        #pragma unroll
        for (int j=0;j<8;++j) tmp[j] = T[seg*8+j][cl];
        size_t row = (size_t)bl*c.Cpad + c.Din + ch0 + cl;
        *(uint4*)(c.Ft + row*DPITCH + n0 + seg*8) = *(const uint4*)tmp;
    }
}

// ---------------------------------------------------------------------------
// diffuse_k: 128m x 64c tile, flat (batch x channel) c-tiling, XCD-pinned.
// (Unchanged from the proven 5319us version.)
// ---------------------------------------------------------------------------
__global__ __launch_bounds__(256) void diffuse_k(DiffCfg ca, DiffCfg cb, int na,
                                                 const u16* __restrict__ asq){
    int bi = blockIdx.x;
    DiffCfg c = ca;
    if (bi >= na){ c = cb; bi -= na; }
    int xcd = bi & 7, m8 = bi >> 3;
    int tg = m8 / 12, s = m8 % 12;
    int t = tg*8 + xcd;
    if (t >= c.T) return;
    int y = s % 3, k = s / 3;
    int fc0;
    if (c.tpb){
        int blb = t / c.tpb, tb = t - blb*c.tpb;
        fc0 = blb*c.Cpad + c.coff0 + tb*64;
    } else {
        fc0 = t*64;
    }
    int bl0  = fc0 / c.Cpad;
    int rem0 = fc0 - bl0*c.Cpad;

    const u16* A    = asq + (size_t)k*AROWS*DPITCH;
    const u16* Bt_g = c.Ft + (size_t)fc0*DPITCH;

    int m0 = y * 128;
    int tid = threadIdx.x;
    int wv = tid >> 6, lane = tid & 63, l15 = lane & 15, quad = lane >> 4;
    int lr = lane >> 3, ls = lane & 7;

    __shared__ u16 As[128*64];
    __shared__ u16 Bs[64*64];

    f32x4 acc[2][4];
    #pragma unroll
    for (int i2=0;i2<2;++i2)
        #pragma unroll
        for (int j=0;j<4;++j) acc[i2][j] = (f32x4){0.f,0.f,0.f,0.f};

    for (int k0 = 0; k0 < N_; k0 += 64){
        #pragma unroll
        for (int j=0;j<4;++j){
            int row = wv*32 + j*8 + lr;
            int seg = ls ^ lr;
            gl_lds16(A + (size_t)(m0+row)*DPITCH + k0 + seg*8, &As[(wv*32 + j*8)*64]);
        }
        #pragma unroll
        for (int j=0;j<2;++j){
            int row = wv*16 + j*8 + lr;
            int seg = ls ^ lr;
            gl_lds16(Bt_g + (size_t)row*DPITCH + k0 + seg*8, &Bs[(wv*16 + j*8)*64]);
        }
        __syncthreads();
        #pragma unroll
        for (int ks = 0; ks < 64; ks += 32){
            int sw = (((ks>>3) + quad) ^ (l15 & 7)) << 3;
            short8 a0 = *(const short8*)&As[(wv*32      + l15)*64 + sw];
            short8 a1 = *(const short8*)&As[(wv*32 + 16 + l15)*64 + sw];
            short8 b0 = *(const short8*)&Bs[(     l15)*64 + sw];
            short8 b1 = *(const short8*)&Bs[(16 + l15)*64 + sw];
            short8 b2 = *(const short8*)&Bs[(32 + l15)*64 + sw];
            short8 b3 = *(const short8*)&Bs[(48 + l15)*64 + sw];
            acc[0][0] = __builtin_amdgcn_mfma_f32_16x16x32_bf16(a0,b0,acc[0][0],0,0,0);
            acc[0][1] = __builtin_amdgcn_mfma_f32_16x16x32_bf16(a0,b1,acc[0][1],0,0,0);
            acc[0][2] = __builtin_amdgcn_mfma_f32_16x16x32_bf16(a0,b2,acc[0][2],0,0,0);
            acc[0][3] = __builtin_amdgcn_mfma_f32_16x16x32_bf16(a0,b3,acc[0][3],0,0,0);
            acc[1][0] = __builtin_amdgcn_mfma_f32_16x16x32_bf16(a1,b0,acc[1][0],0,0,0);
            acc[1][1] = __builtin_amdgcn_mfma_f32_16x16x32_bf16(a1,b1,acc[1][1],0,0,0);
            acc[1][2] = __builtin_amdgcn_mfma_f32_16x16x32_bf16(a1,b2,acc[1][2],0,0,0);
            acc[1][3] = __builtin_amdgcn_mfma_f32_16x16x32_bf16(a1,b3,acc[1][3],0,0,0);
        }
        __syncthreads();
    }
    #pragma unroll
    for (int j=0;j<4;++j){
        int d  = j*16 + l15;
        int cr = rem0 + d;
        int wrap = (cr >= c.Cpad) ? 1 : 0;
        int bl = bl0 + wrap;
        int cc = wrap ? (cr - c.Cpad) : cr;
        int ok = (fc0 + d) < c.fcmax;
        u16* Cm = c.F + (size_t)bl*N_*c.KCP + (size_t)(k+1)*c.C + cc;
        #pragma unroll
        for (int i2=0;i2<2;++i2){
            #pragma unroll
            for (int r=0;r<4;++r){
                int m = m0 + wv*32 + i2*16 + quad*4 + r;
                if (ok && m < N_) Cm[(size_t)m*c.KCP] = f2b(acc[i2][j][r]);
            }
        }
    }
}

// ---------------------------------------------------------------------------
// gemm_k: NEW 64m x 64c tile (was 128m x 64c). Counters showed the gemm
// family latency-bound at 2.6 blocks/CU (Occupancy 24%, MfmaUtil 13%):
// grid size, not resources, capped occupancy. 64m doubles the grid
// (20800 = 64*325 exactly -> no partial m-tile, no OOB A-DMA), LDS 16KB.
// 4 waves x 16 rows each, acc[4], 8 MFMA + 4 gl_lds16 per k-iter.
// MODE 0: zr = sigmoid (pitch 256). MODE 1: GRU update.
// ---------------------------------------------------------------------------
template<int MODE>
__global__ __launch_bounds__(256) void gemm_k(GemmCfg ca, GemmCfg cb, int na){
    int bi = blockIdx.x;
    GemmCfg c = ca;
    if (bi >= na){ c = cb; bi -= na; }
    int xcd = bi & 7, q = bi >> 3;
    int cbk = q % c.ct;
    int rt  = (q / c.ct)*8 + xcd;
    if (rt >= c.gy) return;
    int r0 = rt * 64;
    int c0 = cbk * 64;
    int tid = threadIdx.x;
    int wv = tid >> 6, lane = tid & 63, l15 = lane & 15, quad = lane >> 4;
    int lr = lane >> 3, ls = lane & 7;

    __shared__ u16 As[64*64];
    __shared__ u16 Bs[64*64];

    f32x4 acc[4];
    #pragma unroll
    for (int j=0;j<4;++j) acc[j] = (f32x4){0.f,0.f,0.f,0.f};

    for (int k0 = 0; k0 < c.KCP; k0 += 64){
        #pragma unroll
        for (int j=0;j<2;++j){
            int row = wv*16 + j*8 + lr;
            int seg = ls ^ lr;
            gl_lds16(c.Fb + (size_t)(r0+row)*c.KCP + k0 + seg*8, &As[(wv*16 + j*8)*64]);
            gl_lds16(c.Wt + (size_t)(c0+row)*c.KCP + k0 + seg*8, &Bs[(wv*16 + j*8)*64]);
        }
        __syncthreads();
        #pragma unroll
        for (int ks = 0; ks < 64; ks += 32){
            int sw = (((ks>>3) + quad) ^ (l15 & 7)) << 3;
            short8 a0 = *(const short8*)&As[(wv*16 + l15)*64 + sw];
            short8 b0 = *(const short8*)&Bs[(     l15)*64 + sw];
            short8 b1 = *(const short8*)&Bs[(16 + l15)*64 + sw];
            short8 b2 = *(const short8*)&Bs[(32 + l15)*64 + sw];
            short8 b3 = *(const short8*)&Bs[(48 + l15)*64 + sw];
            acc[0] = __builtin_amdgcn_mfma_f32_16x16x32_bf16(a0,b0,acc[0],0,0,0);
            acc[1] = __builtin_amdgcn_mfma_f32_16x16x32_bf16(a0,b1,acc[1],0,0,0);
            acc[2] = __builtin_amdgcn_mfma_f32_16x16x32_bf16(a0,b2,acc[2],0,0,0);
            acc[3] = __builtin_amdgcn_mfma_f32_16x16x32_bf16(a0,b3,acc[3],0,0,0);
        }
        __syncthreads();
    }
    #pragma unroll
    for (int j=0;j<4;++j){
        int cc = c0 + j*16 + l15;
        #pragma unroll
        for (int r=0;r<4;++r){
            int gr = r0 + wv*16 + quad*4 + r;
            if (gr >= c.rows) continue;
            float v = acc[j][r] + c.bias[cc];
            if (MODE == 0){
                v = 1.f/(1.f + __expf(-v));
                c.zr[(size_t)gr*256 + cc] = v;
            } else {
                float hc   = tanhf(v);
                float z    = c.zr[(size_t)gr*256 + cc];
                float hold = c.hb[(size_t)gr*128 + cc];
                c.hb[(size_t)gr*128 + cc] = z*hold + (1.f - z)*hc;
            }
        }
    }
}

// ---------------------------------------------------------------------------
__global__ __launch_bounds__(256) void proj(const float* __restrict__ h1,
                                            const float* __restrict__ Wp,
                                            const float* __restrict__ bp,
                                            float* __restrict__ xdec,
                                            float* __restrict__ out, int t){
    int row  = blockIdx.x * 4 + (threadIdx.x >> 6);
    int lane = threadIdx.x & 63;
    float v0 = h1[(size_t)row*128 + lane];
    float v1 = h1[(size_t)row*128 + 64 + lane];
    float w00 = Wp[lane*2+0],      w01 = Wp[lane*2+1];
    float w10 = Wp[(64+lane)*2+0], w11 = Wp[(64+lane)*2+1];
    float a0 = v0*w00 + v1*w10;
    float a1 = v0*w01 + v1*w11;
    #pragma unroll
    for (int off=32; off>0; off>>=1){
        a0 += __shfl_down(a0, off);
        a1 += __shfl_down(a1, off);
    }
    if (lane == 0){
        a0 += bp[0];
        a1 += bp[1];
        xdec[(size_t)row*2+0] = a0;
        xdec[(size_t)row*2+1] = a1;
        int b = row / N_, n = row % N_;
        size_t o = ((size_t)(b*T_ + t)*N_ + n)*2;
        out[o]   = a0;
        out[o+1] = a1;
    }
}

// ---------------------------------------------------------------------------
struct Layer {
    u16 *F, *Ft; float *zr; float *h;
    const u16 *Wg, *Wc; const float *bg, *bc;
    int C, KCP, Din, Cpad;
};

extern "C" void kernel_launch(void* const* d_in, const int* in_sizes, int n_in,
                              void* d_out, int out_size, void* d_ws, size_t ws_size,
                              hipStream_t stream){
    float* out = (float*)d_out;

    char* pb = (char*)d_ws;
    auto alloc = [&](size_t bytes)->void*{
        void* r = (void*)pb;
        pb += (bytes + 255) & ~(size_t)255;
        return r;
    };

    int* flag = (int*)alloc(16);
    sniff<<<1, 64, 0, stream>>>(d_in[2], flag);

    const int idxs[11] = {0,4,6,8,10,12,14,16,18,19,20};
    float* cw[21] = {nullptr};
    CvtArgs ca;
    int maxn = 0;
    for (int ii = 0; ii < 11; ++ii){
        int i = idxs[ii];
        int n = in_sizes[i];
        cw[i] = (float*)alloc((size_t)n*4);
        ca.src[ii] = d_in[i];
        ca.dst[ii] = cw[i];
        ca.n[ii]   = n;
        if (n > maxn) maxn = n;
    }
    cvt_all<<<dim3((maxn+255)/256, 11), 256, 0, stream>>>(ca, flag);
    const float* src = cw[0];

    float* msq  = (float*)alloc((size_t)4*N_*N_*4);
    float* h0   = (float*)alloc((size_t)BN*H_*4);
    float* h1   = (float*)alloc((size_t)BN*H_*4);
    float* xdec = (float*)alloc((size_t)BN*DIN*4);
    u16*   asq  = (u16*)alloc((size_t)4*AROWS*DPITCH*2);

    const int widx[8]  = {3,5,7,9,11,13,15,17};
    const int wKC[8]   = {650,650,1280,1280,650,650,1280,1280};
    const int wNout[8] = {256,128,256,128,256,128,256,128};
    u16* wt[8];
    for (int i=0;i<8;++i){
        int KCpad = (wKC[i] + 63) & ~63;
        wt[i] = (u16*)alloc((size_t)wNout[i]*KCpad*2);
        wtrans<<<dim3(KCpad/64, wNout[i]/64), 256, 0, stream>>>(d_in[widx[i]], wt[i], wKC[i], wNout[i], KCpad, flag);
    }

    {
        dim3 g((N_+15)/16, (N_+15)/16, 2), b(16,16);
        support_prep<<<g, b, 0, stream>>>(d_in[2], flag, msq);
        int tot = 4*AROWS*DPITCH;
        asq_prep<<<dim3((tot+255)/256), 256, 0, stream>>>(msq, asq);
    }
    hipMemsetAsync(h0, 0, sizeof(float)*(size_t)BN*H_*2, stream);  // h0 and h1

    // ---- buffer sets: dual (layer-pipelined encoder) if ws allows ----
    size_t fixed = (size_t)(pb - (char*)d_ws);
    size_t need0 = (size_t)BN*256*4 + (size_t)BN*704*2  + (size_t)B_*130*DPITCH*2;
    size_t need1 = (size_t)BN*256*4 + (size_t)BN*1280*2 + (size_t)B_*256*DPITCH*2;
    bool dual = (fixed + need0 + need1 + (4<<20)) <= ws_size;

    auto mkFill = [&](Layer& L, const float* x, long xbs, int b0, int Bc)->FillCfg{
        return FillCfg{L.F, L.Ft, x, L.h, xbs, L.C, L.KCP, L.Cpad, L.Din, b0,
                       6*((L.C+63)>>6)*Bc};
    };
    auto mkD1 = [&](Layer& L, int Bc)->DiffCfg{
        int fcmax = Bc*L.Cpad;
        int T = fcmax >> 6;
        return DiffCfg{L.F, L.Ft, L.C, L.KCP, L.Cpad, 0, 0, T, fcmax,
                       12*(((T+7)/8)*8)};
    };
    auto mkD2 = [&](Layer& L, int Bc)->DiffCfg{
        int T = Bc*2;
        return DiffCfg{L.F, L.Ft, L.C, L.KCP, L.Cpad, L.Din, 2, T, Bc*L.Cpad,
                       12*(((T+7)/8)*8)};
    };
    auto mkG0 = [&](Layer& L, int b0, int Bc)->GemmCfg{
        int rows = Bc*N_, gy = (rows+63)/64;
        return GemmCfg{L.F, L.Wg, L.bg, L.zr, L.h + (size_t)b0*N_*H_,
                       L.KCP, rows, gy, 4, 8*((gy+7)/8)*4};
    };
    auto mkG1 = [&](Layer& L, int b0, int Bc)->GemmCfg{
        int rows = Bc*N_, gy = (rows+63)/64;
        return GemmCfg{L.F, L.Wc, L.bc, L.zr, L.h + (size_t)b0*N_*H_,
                       L.KCP, rows, gy, 2, 8*((gy+7)/8)*2};
    };
    auto mkRh = [&](Layer& L, int b0, int Bc)->RhCfg{
        return RhCfg{L.F, L.Ft, L.zr, L.h, L.KCP, L.Cpad, L.Din, b0, 12*Bc};
    };
    auto runCellSeq = [&](Layer& L, const float* x, long xbs, int b0, int Bc){
        FillCfg f = mkFill(L, x, xbs, b0, Bc);
        fill_k<<<dim3(f.nb), 256, 0, stream>>>(f, f, f.nb);
        DiffCfg d1 = mkD1(L, Bc);
        diffuse_k<<<dim3(d1.nb), 256, 0, stream>>>(d1, d1, d1.nb, asq);
        GemmCfg g0 = mkG0(L, b0, Bc);
        gemm_k<0><<<dim3(g0.nb), 256, 0, stream>>>(g0, g0, g0.nb);
        RhCfg r = mkRh(L, b0, Bc);
        rhfill_k<<<dim3(r.nb), 256, 0, stream>>>(r, r, r.nb);
        DiffCfg d2 = mkD2(L, Bc);
        diffuse_k<<<dim3(d2.nb), 256, 0, stream>>>(d2, d2, d2.nb, asq);
        GemmCfg g1 = mkG1(L, b0, Bc);
        gemm_k<1><<<dim3(g1.nb), 256, 0, stream>>>(g1, g1, g1.nb);
    };

    if (dual){
        float* zr0 = (float*)alloc((size_t)BN*256*4);
        u16*   F0  = (u16*)alloc((size_t)BN*704*2);
        u16*   Ft0 = (u16*)alloc((size_t)B_*130*DPITCH*2);
        float* zr1 = (float*)alloc((size_t)BN*256*4);
        u16*   F1  = (u16*)alloc((size_t)BN*1280*2);
        u16*   Ft1 = (u16*)alloc((size_t)B_*256*DPITCH*2);
        alloc(1<<19);  // slack for OOB-row DMA

        // One-time zero of F0 so its pad columns (650..703) are finite zeros
        // forever (every later write is f2b(finite)); Wt zero-rows annihilate.
        hipMemsetAsync(F0, 0, (size_t)BN*704*2, stream);

        Layer E0{F0, Ft0, zr0, h0, wt[0], wt[1], cw[4],  cw[6],  130, 704,  2,   130};
        Layer E1{F1, Ft1, zr1, h1, wt[2], wt[3], cw[8],  cw[10], 256, 1280, 128, 256};
        Layer D0{F0, Ft0, zr0, h0, wt[4], wt[5], cw[12], cw[14], 130, 704,  2,   130};
        Layer D1{F1, Ft1, zr1, h1, wt[6], wt[7], cw[16], cw[18], 256, 1280, 128, 256};

        // ------- encoder: layer-pipelined super-steps -------
        for (int s = 0; s <= T_; ++s){
            bool has0 = (s < T_), has1 = (s >= 1);
            const float* x0 = src + (size_t)s*N_*DIN;
            FillCfg f0 = mkFill(E0, x0, (long)T_*N_*DIN, 0, B_);
            FillCfg f1 = mkFill(E1, h0, (long)N_*H_,     0, B_);
            if (has0 && has1) fill_k<<<dim3(f0.nb+f1.nb),256,0,stream>>>(f0, f1, f0.nb);
            else if (has0)    fill_k<<<dim3(f0.nb),256,0,stream>>>(f0, f0, f0.nb);
            else              fill_k<<<dim3(f1.nb),256,0,stream>>>(f1, f1, f1.nb);

            DiffCfg a1 = mkD1(E0, B_), b1 = mkD1(E1, B_);
            if (has0 && has1) diffuse_k<<<dim3(a1.nb+b1.nb),256,0,stream>>>(a1, b1, a1.nb, asq);
            else if (has0)    diffuse_k<<<dim3(a1.nb),256,0,stream>>>(a1, a1, a1.nb, asq);
            else              diffuse_k<<<dim3(b1.nb),256,0,stream>>>(b1, b1, b1.nb, asq);

            GemmCfg ga = mkG0(E0, 0, B_), gb = mkG0(E1, 0, B_);
            if (has0 && has1) gemm_k<0><<<dim3(ga.nb+gb.nb),256,0,stream>>>(ga, gb, ga.nb);
            else if (has0)    gemm_k<0><<<dim3(ga.nb),256,0,stream>>>(ga, ga, ga.nb);
            else              gemm_k<0><<<dim3(gb.nb),256,0,stream>>>(gb, gb, gb.nb);

            RhCfg ra = mkRh(E0, 0, B_), rb = mkRh(E1, 0, B_);
            if (has0 && has1) rhfill_k<<<dim3(ra.nb+rb.nb),256,0,stream>>>(ra, rb, ra.nb);
            else if (has0)    rhfill_k<<<dim3(ra.nb),256,0,stream>>>(ra, ra, ra.nb);
            else              rhfill_k<<<dim3(rb.nb),256,0,stream>>>(rb, rb, rb.nb);

            DiffCfg a2 = mkD2(E0, B_), b2 = mkD2(E1, B_);
            if (has0 && has1) diffuse_k<<<dim3(a2.nb+b2.nb),256,0,stream>>>(a2, b2, a2.nb, asq);
            else if (has0)    diffuse_k<<<dim3(a2.nb),256,0,stream>>>(a2, a2, a2.nb, asq);
            else              diffuse_k<<<dim3(b2.nb),256,0,stream>>>(b2, b2, b2.nb, asq);

            GemmCfg ha = mkG1(E0, 0, B_), hb = mkG1(E1, 0, B_);
            if (has0 && has1) gemm_k<1><<<dim3(ha.nb+hb.nb),256,0,stream>>>(ha, hb, ha.nb);
            else if (has0)    gemm_k<1><<<dim3(ha.nb),256,0,stream>>>(ha, ha, ha.nb);
            else              gemm_k<1><<<dim3(hb.nb),256,0,stream>>>(hb, hb, hb.nb);
        }

        // ------- decoder: serial (proj feedback) -------
        hipMemsetAsync(xdec, 0, sizeof(float)*(size_t)BN*DIN, stream);
        for (int t = 0; t < T_; ++t){
            runCellSeq(D0, xdec, (long)N_*DIN, 0, B_);
            runCellSeq(D1, h0,   (long)N_*H_,  0, B_);
            proj<<<dim3(BN/4), 256, 0, stream>>>(h1, cw[19], cw[20], xdec, out, t);
        }
    } else {
        // ------- fallback: sequential with adaptive chunking -------
        size_t perb = (size_t)N_*1280*2 + (size_t)N_*256*4 + (size_t)256*DPITCH*2;
        int Bc = 64;
        while (Bc > 2 && fixed + (1<<20) + (size_t)Bc*perb > ws_size) Bc >>= 1;
        float* zr = (float*)alloc((size_t)Bc*N_*256*4);
        u16*   F  = (u16*)alloc((size_t)Bc*N_*1280*2);
        u16*   Ft = (u16*)alloc((size_t)Bc*256*DPITCH*2);
        alloc(1<<19);

        hipMemsetAsync(F, 0, (size_t)Bc*N_*1280*2, stream);

        Layer SE0{F, Ft, zr, h0, wt[0], wt[1], cw[4],  cw[6],  130, 704,  2,   130};
        Layer SE1{F, Ft, zr, h1, wt[2], wt[3], cw[8],  cw[10], 256, 1280, 128, 256};
        Layer SD0{F, Ft, zr, h0, wt[4], wt[5], cw[12], cw[14], 130, 704,  2,   130};
        Layer SD1{F, Ft, zr, h1, wt[6], wt[7], cw[16], cw[18], 256, 1280, 128, 256};

        for (int t = 0; t < T_; ++t){
            for (int b0 = 0; b0 < B_; b0 += Bc)
                runCellSeq(SE0, src + (size_t)t*N_*DIN, (long)T_*N_*DIN, b0, Bc);
            for (int b0 = 0; b0 < B_; b0 += Bc)
                runCellSeq(SE1, h0, (long)N_*H_, b0, Bc);
        }
        hipMemsetAsync(xdec, 0, sizeof(float)*(size_t)BN*DIN, stream);
        for (int t = 0; t < T_; ++t){
            for (int b0 = 0; b0 < B_; b0 += Bc)
                runCellSeq(SD0, xdec, (long)N_*DIN, b0, Bc);
            for (int b0 = 0; b0 < B_; b0 += Bc)
                runCellSeq(SD1, h0, (long)N_*H_, b0, Bc);
            proj<<<dim3(BN/4), 256, 0, stream>>>(h1, cw[19], cw[20], xdec, out, t);
        }
    }
}